// Round 2
// baseline (567.918 us; speedup 1.0000x reference)
//
#include <hip/hip_runtime.h>
#include <stdint.h>

#define BATCH 8
#define L_SEQ 2048
#define D_MODEL 512
#define TOPK 7
#define BM 128
#define BN 128
#define BK 32
#define LK 40   // LDS row stride in bf16 elems (80 B = 5*16B: b128-aligned every row)

typedef __attribute__((ext_vector_type(8))) short bf16x8;
typedef __attribute__((ext_vector_type(4))) float f32x4;
typedef unsigned short u16;
typedef unsigned int u32;

__device__ __forceinline__ u16 f2bf(float f) {
    union { float f; u32 u; } v; v.f = f;
    u32 r = v.u + 0x7FFFu + ((v.u >> 16) & 1u);   // round-to-nearest-even
    return (u16)(r >> 16);
}
__device__ __forceinline__ float bf2f(u16 h) {
    union { u32 u; float f; } v; v.u = ((u32)h) << 16; return v.f;
}

// ---------------- fp32-accurate GEMM via bf16 hi/lo split, C = A * B^T ----------------
// ASRC: 0 = A fp32 (split during staging), 1 = A pre-split bf16 pair (Ap=hi, Ap2=lo).
// CORR: 0 = write hi/lo bf16 C (+bias);  1 = wrapped-diagonal reduction into corrOut.
// acc += Ahi*Bhi + Ahi*Blo + Alo*Bhi  (bf16 products are exact in fp32; lo*lo ~1.6e-5 rel, dropped)
template<int ASRC, int CORR>
__global__ __launch_bounds__(256) void gemm_split(
    const void* __restrict__ Ap, const void* __restrict__ Ap2,
    const u16* __restrict__ Bhi, const u16* __restrict__ Blo,
    const float* __restrict__ bias, u16* __restrict__ Chi, u16* __restrict__ Clo,
    float* __restrict__ corrOut, int N, int K, long aStride, long bStride)
{
    __shared__ __align__(16) u16 lAhi[BM * LK];
    __shared__ __align__(16) u16 lAlo[BM * LK];
    __shared__ __align__(16) u16 lBhi[BN * LK];
    __shared__ __align__(16) u16 lBlo[BN * LK];
    __shared__ float diag[256];

    const int tid = threadIdx.x;
    const int bn = blockIdx.x, bm = blockIdx.y, bz = blockIdx.z;
    const int lane = tid & 63, wave = tid >> 6;
    const int wm = wave >> 1, wn = wave & 1;
    const int l15 = lane & 15, quad = lane >> 4;

    const u16* BH = Bhi + (long)bz * bStride;
    const u16* BL = Blo + (long)bz * bStride;
    const float* Af = (const float*)Ap + (long)bz * aStride;
    const u16* AH = (const u16*)Ap + (long)bz * aStride;
    const u16* AL = (const u16*)Ap2 + (long)bz * aStride;

    if (CORR) diag[tid] = 0.0f;

    f32x4 acc[4][4] = {};

    for (int k0 = 0; k0 < K; k0 += BK) {
        if (ASRC == 1) {
            #pragma unroll
            for (int j = 0; j < 2; ++j) {
                int idx = tid + j * 256;                  // 128x32 tile / 8
                int row = idx >> 2, c8 = (idx & 3) * 8;
                long src = (long)(bm * BM + row) * K + k0 + c8;
                *(uint4*)&lAhi[row * LK + c8] = *(const uint4*)(AH + src);
                *(uint4*)&lAlo[row * LK + c8] = *(const uint4*)(AL + src);
            }
        } else {
            #pragma unroll
            for (int j = 0; j < 4; ++j) {
                int idx = tid + j * 256;                  // 128x32 tile / 4
                int row = idx >> 3, c4 = (idx & 7) * 4;
                float4 va = *(const float4*)(Af + (long)(bm * BM + row) * K + k0 + c4);
                ushort4 h, l;
                h.x = f2bf(va.x); l.x = f2bf(va.x - bf2f(h.x));
                h.y = f2bf(va.y); l.y = f2bf(va.y - bf2f(h.y));
                h.z = f2bf(va.z); l.z = f2bf(va.z - bf2f(h.z));
                h.w = f2bf(va.w); l.w = f2bf(va.w - bf2f(h.w));
                *(ushort4*)&lAhi[row * LK + c4] = h;
                *(ushort4*)&lAlo[row * LK + c4] = l;
            }
        }
        #pragma unroll
        for (int j = 0; j < 2; ++j) {
            int idx = tid + j * 256;
            int row = idx >> 2, c8 = (idx & 3) * 8;
            long src = (long)(bn * BN + row) * K + k0 + c8;
            *(uint4*)&lBhi[row * LK + c8] = *(const uint4*)(BH + src);
            *(uint4*)&lBlo[row * LK + c8] = *(const uint4*)(BL + src);
        }
        __syncthreads();

        bf16x8 faH[4], faL[4], fbH[4], fbL[4];
        #pragma unroll
        for (int i = 0; i < 4; ++i) {
            int off = (wm * 64 + i * 16 + l15) * LK + quad * 8;
            faH[i] = *(const bf16x8*)&lAhi[off];
            faL[i] = *(const bf16x8*)&lAlo[off];
        }
        #pragma unroll
        for (int j = 0; j < 4; ++j) {
            int off = (wn * 64 + j * 16 + l15) * LK + quad * 8;
            fbH[j] = *(const bf16x8*)&lBhi[off];
            fbL[j] = *(const bf16x8*)&lBlo[off];
        }
        #pragma unroll
        for (int i = 0; i < 4; ++i)
            #pragma unroll
            for (int j = 0; j < 4; ++j) {
                acc[i][j] = __builtin_amdgcn_mfma_f32_16x16x32_bf16(faH[i], fbH[j], acc[i][j], 0, 0, 0);
                acc[i][j] = __builtin_amdgcn_mfma_f32_16x16x32_bf16(faH[i], fbL[j], acc[i][j], 0, 0, 0);
                acc[i][j] = __builtin_amdgcn_mfma_f32_16x16x32_bf16(faL[i], fbH[j], acc[i][j], 0, 0, 0);
            }
        __syncthreads();
    }

    if (!CORR) {
        #pragma unroll
        for (int i = 0; i < 4; ++i) {
            int row = bm * BM + wm * 64 + i * 16 + quad * 4;
            #pragma unroll
            for (int j = 0; j < 4; ++j) {
                int col = bn * BN + wn * 64 + j * 16 + l15;
                float bvv = bias[col];
                #pragma unroll
                for (int r = 0; r < 4; ++r) {
                    float val = acc[i][j][r] + bvv;
                    u16 h = f2bf(val);
                    Chi[(long)(row + r) * N + col] = h;
                    Clo[(long)(row + r) * N + col] = f2bf(val - bf2f(h));
                }
            }
        }
    } else {
        #pragma unroll
        for (int i = 0; i < 4; ++i) {
            int dt = wm * 64 + i * 16 + quad * 4;
            #pragma unroll
            for (int j = 0; j < 4; ++j) {
                int ds = wn * 64 + j * 16 + l15;
                #pragma unroll
                for (int r = 0; r < 4; ++r)
                    atomicAdd(&diag[dt + r - ds + 127], acc[i][j][r]);
            }
        }
        __syncthreads();
        if (tid < 255) {
            int tau = ((bm - bn) * BM + tid - 127 + 2 * L_SEQ) & (L_SEQ - 1);
            atomicAdd(&corrOut[bz * L_SEQ + tau], diag[tid]);
        }
    }
}

// ---------------- plain bf16 GEMM (V projection, final projection) ----------------
template<int ABF16, int OUTBF16>
__global__ __launch_bounds__(256) void gemm_plain(
    const void* __restrict__ Ap, const u16* __restrict__ Bt,
    const float* __restrict__ bias, void* __restrict__ Cp, int N, int K)
{
    __shared__ __align__(16) u16 lA[BM * LK];
    __shared__ __align__(16) u16 lB[BN * LK];

    const int tid = threadIdx.x;
    const int bn = blockIdx.x, bm = blockIdx.y;
    const int lane = tid & 63, wave = tid >> 6;
    const int wm = wave >> 1, wn = wave & 1;
    const int l15 = lane & 15, quad = lane >> 4;

    const float* Af = (const float*)Ap;
    const u16* Ah = (const u16*)Ap;

    f32x4 acc[4][4] = {};

    for (int k0 = 0; k0 < K; k0 += BK) {
        if (ABF16) {
            #pragma unroll
            for (int j = 0; j < 2; ++j) {
                int idx = tid + j * 256;
                int row = idx >> 2, c8 = (idx & 3) * 8;
                *(uint4*)&lA[row * LK + c8] =
                    *(const uint4*)(Ah + (long)(bm * BM + row) * K + k0 + c8);
            }
        } else {
            #pragma unroll
            for (int j = 0; j < 4; ++j) {
                int idx = tid + j * 256;
                int row = idx >> 3, c4 = (idx & 7) * 4;
                float4 va = *(const float4*)(Af + (long)(bm * BM + row) * K + k0 + c4);
                ushort4 pa; pa.x = f2bf(va.x); pa.y = f2bf(va.y);
                            pa.z = f2bf(va.z); pa.w = f2bf(va.w);
                *(ushort4*)&lA[row * LK + c4] = pa;
            }
        }
        #pragma unroll
        for (int j = 0; j < 2; ++j) {
            int idx = tid + j * 256;
            int row = idx >> 2, c8 = (idx & 3) * 8;
            *(uint4*)&lB[row * LK + c8] =
                *(const uint4*)(Bt + (long)(bn * BN + row) * K + k0 + c8);
        }
        __syncthreads();

        bf16x8 fa[4], fb[4];
        #pragma unroll
        for (int i = 0; i < 4; ++i)
            fa[i] = *(const bf16x8*)&lA[(wm * 64 + i * 16 + l15) * LK + quad * 8];
        #pragma unroll
        for (int j = 0; j < 4; ++j)
            fb[j] = *(const bf16x8*)&lB[(wn * 64 + j * 16 + l15) * LK + quad * 8];
        #pragma unroll
        for (int i = 0; i < 4; ++i)
            #pragma unroll
            for (int j = 0; j < 4; ++j)
                acc[i][j] = __builtin_amdgcn_mfma_f32_16x16x32_bf16(fa[i], fb[j], acc[i][j], 0, 0, 0);
        __syncthreads();
    }

    #pragma unroll
    for (int i = 0; i < 4; ++i) {
        int row = bm * BM + wm * 64 + i * 16 + quad * 4;
        #pragma unroll
        for (int j = 0; j < 4; ++j) {
            int col = bn * BN + wn * 64 + j * 16 + l15;
            float bvv = bias[col];
            #pragma unroll
            for (int r = 0; r < 4; ++r) {
                float val = acc[i][j][r] + bvv;
                if (OUTBF16) ((u16*)Cp)[(long)(row + r) * N + col] = f2bf(val);
                else         ((float*)Cp)[(long)(row + r) * N + col] = val;
            }
        }
    }
}

// Wt[n][k] = W[k][n], fp32 -> bf16 (SPLIT: hi + lo pair)
template<int SPLIT>
__global__ __launch_bounds__(256) void transposeW(
    const float* __restrict__ src, u16* __restrict__ dhi, u16* __restrict__ dlo)
{
    __shared__ float t[32][33];
    int tx = threadIdx.x & 31, ty = threadIdx.x >> 5;
    int c0 = blockIdx.x * 32, r0 = blockIdx.y * 32;
    #pragma unroll
    for (int r = ty; r < 32; r += 8)
        t[r][tx] = src[(long)(r0 + r) * D_MODEL + c0 + tx];
    __syncthreads();
    #pragma unroll
    for (int r = ty; r < 32; r += 8) {
        float v = t[tx][r];
        u16 h = f2bf(v);
        dhi[(long)(c0 + r) * D_MODEL + r0 + tx] = h;
        if (SPLIT) dlo[(long)(c0 + r) * D_MODEL + r0 + tx] = f2bf(v - bf2f(h));
    }
}

// One block. g[tau] = sum_b raw[b][tau]; top-7 (lowest-index tie-break);
// weights = raw[b][idx]/512 -> per-b softmax.
__global__ __launch_bounds__(256) void select_topk(
    const float* __restrict__ raw, int* __restrict__ selIdx, float* __restrict__ selW)
{
    __shared__ float g[L_SEQ];
    __shared__ float rv[256];
    __shared__ int   ri[256];
    __shared__ int   sidx[TOPK];
    __shared__ float wbuf[BATCH][TOPK];
    int tid = threadIdx.x;
    for (int t = tid; t < L_SEQ; t += 256) {
        float s = 0.0f;
        #pragma unroll
        for (int b = 0; b < BATCH; ++b) s += raw[b * L_SEQ + t];
        g[t] = s;
    }
    __syncthreads();
    for (int it = 0; it < TOPK; ++it) {
        float best = -1e30f; int bi = 0x7fffffff;
        for (int t = tid; t < L_SEQ; t += 256) {
            float v = g[t];
            if (v > best || (v == best && t < bi)) { best = v; bi = t; }
        }
        rv[tid] = best; ri[tid] = bi;
        __syncthreads();
        for (int s = 128; s > 0; s >>= 1) {
            if (tid < s) {
                float v2 = rv[tid + s]; int i2 = ri[tid + s];
                if (v2 > rv[tid] || (v2 == rv[tid] && i2 < ri[tid])) { rv[tid] = v2; ri[tid] = i2; }
            }
            __syncthreads();
        }
        if (tid == 0) { sidx[it] = ri[0]; g[ri[0]] = -1e30f; }
        __syncthreads();
    }
    if (tid < BATCH * TOPK) {
        int b = tid / TOPK, k = tid % TOPK;
        wbuf[b][k] = raw[b * L_SEQ + sidx[k]] * (1.0f / 512.0f);
    }
    __syncthreads();
    if (tid < BATCH) {
        float mx = -1e30f;
        #pragma unroll
        for (int k = 0; k < TOPK; ++k) mx = fmaxf(mx, wbuf[tid][k]);
        float e[TOPK]; float sum = 0.0f;
        #pragma unroll
        for (int k = 0; k < TOPK; ++k) { e[k] = expf(wbuf[tid][k] - mx); sum += e[k]; }
        #pragma unroll
        for (int k = 0; k < TOPK; ++k) selW[tid * TOPK + k] = e[k] / sum;
    }
    if (tid < TOPK) selIdx[tid] = sidx[tid];
}

// attn[b,l,:] = sum_k w[b][k] * V[b,(l+idx[k])%L,:]  (bf16 in/out, 8 elems/thread)
__global__ __launch_bounds__(256) void gather_agg(
    const u16* __restrict__ V, const int* __restrict__ selIdx,
    const float* __restrict__ selW, u16* __restrict__ outB)
{
    __shared__ int si[TOPK];
    __shared__ float sw[TOPK];
    long flat = (long)blockIdx.x * 256 + threadIdx.x;     // over B*L*D/8 uint4s
    int b  = (int)(flat >> 17);                            // L*D/8 = 2^17 per b
    int l  = (int)((flat >> 6) & (L_SEQ - 1));
    int d8 = (int)(flat & 63);
    if (threadIdx.x < TOPK) {
        si[threadIdx.x] = selIdx[threadIdx.x];
        sw[threadIdx.x] = selW[b * TOPK + threadIdx.x];
    }
    __syncthreads();
    const uint4* v8 = (const uint4*)(V + (long)b * L_SEQ * D_MODEL);
    float a[8] = {0,0,0,0,0,0,0,0};
    #pragma unroll
    for (int k = 0; k < TOPK; ++k) {
        int src = (l + si[k]) & (L_SEQ - 1);
        uint4 x = v8[src * 64 + d8];
        float w = sw[k];
        u32 xs[4] = {x.x, x.y, x.z, x.w};
        #pragma unroll
        for (int q = 0; q < 4; ++q) {
            a[q*2]   += w * bf2f((u16)(xs[q] & 0xFFFFu));
            a[q*2+1] += w * bf2f((u16)(xs[q] >> 16));
        }
    }
    uint4 o;
    o.x = (u32)f2bf(a[0]) | ((u32)f2bf(a[1]) << 16);
    o.y = (u32)f2bf(a[2]) | ((u32)f2bf(a[3]) << 16);
    o.z = (u32)f2bf(a[4]) | ((u32)f2bf(a[5]) << 16);
    o.w = (u32)f2bf(a[6]) | ((u32)f2bf(a[7]) << 16);
    ((uint4*)outB)[flat] = o;
}

extern "C" void kernel_launch(void* const* d_in, const int* in_sizes, int n_in,
                              void* d_out, int out_size, void* d_ws, size_t ws_size,
                              hipStream_t stream)
{
    (void)in_sizes; (void)n_in; (void)out_size; (void)ws_size;
    const float* Xq = (const float*)d_in[0];
    const float* Xk = (const float*)d_in[1];
    const float* Xv = (const float*)d_in[2];
    const float* Wq = (const float*)d_in[3];
    const float* bq = (const float*)d_in[4];
    const float* Wk = (const float*)d_in[5];
    const float* bk = (const float*)d_in[6];
    const float* Wv = (const float*)d_in[7];
    const float* bv = (const float*)d_in[8];
    const float* Wo = (const float*)d_in[9];
    const float* bo = (const float*)d_in[10];

    char* ws = (char*)d_ws;
    const long SLAB = (long)BATCH * L_SEQ * D_MODEL * sizeof(u16);   // 16 MB bf16 slab
    u16* Qhi = (u16*)(ws);                 // later reused as attn
    u16* Qlo = (u16*)(ws + SLAB);
    u16* Khi = (u16*)(ws + 2 * SLAB);      // later reused as V
    u16* Klo = (u16*)(ws + 3 * SLAB);
    u16* Wsl = (u16*)(ws + 4 * SLAB);      // 6 x 512KB: Wqhi,Wqlo,Wkhi,Wklo,Wv,Wo
    const long WSZ = (long)D_MODEL * D_MODEL;
    u16* Wqhi = Wsl + 0 * WSZ; u16* Wqlo = Wsl + 1 * WSZ;
    u16* Wkhi = Wsl + 2 * WSZ; u16* Wklo = Wsl + 3 * WSZ;
    u16* Wvb  = Wsl + 4 * WSZ; u16* Wob  = Wsl + 5 * WSZ;
    float* raw = (float*)(ws + 4 * SLAB + 6 * WSZ * sizeof(u16));
    int*   sIdx = (int*)((char*)raw + (long)BATCH * L_SEQ * sizeof(float));
    float* sW   = (float*)(sIdx + 8);
    u16* Vb   = Khi;      // V written after corr frees K
    u16* attn = Qhi;      // attn written after corr frees Q

    dim3 tb(256);
    transposeW<1><<<dim3(16, 16), tb, 0, stream>>>(Wq, Wqhi, Wqlo);
    transposeW<1><<<dim3(16, 16), tb, 0, stream>>>(Wk, Wkhi, Wklo);
    transposeW<0><<<dim3(16, 16), tb, 0, stream>>>(Wv, Wvb, nullptr);
    transposeW<0><<<dim3(16, 16), tb, 0, stream>>>(Wo, Wob, nullptr);
    hipMemsetAsync(raw, 0, (long)BATCH * L_SEQ * sizeof(float), stream);

    // Q/K projections, fp32-accurate (split in/out)
    dim3 gLin(D_MODEL / BN, (BATCH * L_SEQ) / BM, 1);   // (4, 128)
    gemm_split<0, 0><<<gLin, tb, 0, stream>>>(Xq, nullptr, Wqhi, Wqlo, bq,
                                              Qhi, Qlo, nullptr, D_MODEL, D_MODEL, 0, 0);
    gemm_split<0, 0><<<gLin, tb, 0, stream>>>(Xk, nullptr, Wkhi, Wklo, bk,
                                              Khi, Klo, nullptr, D_MODEL, D_MODEL, 0, 0);

    // Batched correlation Q K^T (3-term split) with wrapped-diagonal reduction -> raw[b][tau]
    dim3 gC(L_SEQ / BN, L_SEQ / BM, BATCH);             // (16, 16, 8)
    gemm_split<1, 1><<<gC, tb, 0, stream>>>(Qhi, Qlo, Khi, Klo, nullptr,
                                            nullptr, nullptr, raw,
                                            L_SEQ, D_MODEL,
                                            (long)L_SEQ * D_MODEL, (long)L_SEQ * D_MODEL);

    select_topk<<<1, tb, 0, stream>>>(raw, sIdx, sW);

    // V projection (plain bf16) into Khi slab
    gemm_plain<0, 1><<<gLin, tb, 0, stream>>>(Xv, Wvb, bv, Vb, D_MODEL, D_MODEL);

    gather_agg<<<(BATCH * L_SEQ * D_MODEL / 8) / 256, tb, 0, stream>>>(Vb, sIdx, sW, attn);

    // Final projection: attn (bf16) @ Wo^T + bo -> fp32 d_out
    gemm_plain<1, 0><<<gLin, tb, 0, stream>>>(attn, Wob, bo, d_out, D_MODEL, D_MODEL);
}

// Round 3
// 481.093 us; speedup vs baseline: 1.1805x; 1.1805x over previous
//
#include <hip/hip_runtime.h>
#include <stdint.h>

#define BATCH 8
#define L_SEQ 2048
#define D_MODEL 512
#define TOPK 7
#define BM 128
#define BN 128
#define BK 32

typedef _Float16 f16x8 __attribute__((ext_vector_type(8)));
typedef __attribute__((ext_vector_type(4))) float f32x4;
typedef unsigned short u16;
typedef unsigned int u32;

__device__ __forceinline__ u16 f2h(float f) {
    union { _Float16 h; u16 u; } v; v.h = (_Float16)f; return v.u;
}
__device__ __forceinline__ float h2f(u16 b) {
    union { u16 u; _Float16 h; } v; v.u = b; return (float)v.h;
}

// async 16B/lane global->LDS. Dest is wave-uniform base + lane*16 (m104/m108).
__device__ __forceinline__ void load_lds16(const u16* g, u16* l) {
    __builtin_amdgcn_global_load_lds(
        (const __attribute__((address_space(1))) u32*)(g),
        (__attribute__((address_space(3))) u32*)(l), 16, 0, 0);
}

// ---------------- fp16 MFMA GEMM, C = A * B^T ----------------
// A: M x K row-major f16.  Bt: N x K row-major f16.
// EPI 0: C f16 (+bias)   EPI 1: wrapped-diagonal corr reduction   EPI 2: C f32 (+bias)
// LDS: unpadded 128x32 f16 tiles (64 B rows); 16B chunk c of row r stored at
// slot c ^ ((r>>1)&3)  -> fragment ds_read_b128 is 2-way-bank (free, m136).
// Swizzle realized via per-lane global address in global_load_lds staging.
template<int EPI>
__global__ __launch_bounds__(256, 4) void gemm_f16(
    const u16* __restrict__ A, const u16* __restrict__ Bt,
    const float* __restrict__ bias, void* __restrict__ Cp,
    float* __restrict__ corrOut, int N, int K, long aStride, long bStride)
{
    __shared__ __align__(16) u16 lA[BM * BK];   // 8 KB
    __shared__ __align__(16) u16 lB[BN * BK];   // 8 KB
    __shared__ float diag[256];

    const int tid = threadIdx.x;
    const int bn = blockIdx.x, bm = blockIdx.y, bz = blockIdx.z;
    const int lane = tid & 63, wave = tid >> 6;
    const int wm = wave >> 1, wn = wave & 1;
    const int l15 = lane & 15, quad = lane >> 4;

    A += (long)bz * aStride;
    Bt += (long)bz * bStride;

    if (EPI == 1) diag[tid] = 0.0f;

    // staging slots: s = j*256 + wave*64 + lane, j=0,1; row r = s>>2, chunkslot cs = s&3
    // global chunk for slot: c = cs ^ ((r>>1)&3)
    const int s0 = wave * 64 + lane, s1 = s0 + 256;
    const int r0 = s0 >> 2, c0 = (s0 & 3) ^ ((r0 >> 1) & 3);
    const int r1 = s1 >> 2, c1 = (s1 & 3) ^ ((r1 >> 1) & 3);
    const u16* gA0 = A + (long)(bm * BM + r0) * K + c0 * 8;
    const u16* gA1 = A + (long)(bm * BM + r1) * K + c1 * 8;
    const u16* gB0 = Bt + (long)(bn * BN + r0) * K + c0 * 8;
    const u16* gB1 = Bt + (long)(bn * BN + r1) * K + c1 * 8;
    u16* lA0 = &lA[wave * 512];         // bytes: wave*1024
    u16* lA1 = &lA[2048 + wave * 512];  // j=1 half
    u16* lB0 = &lB[wave * 512];
    u16* lB1 = &lB[2048 + wave * 512];

    f32x4 acc[4][4] = {};

    for (int k0 = 0; k0 < K; k0 += BK) {
        load_lds16(gA0, lA0); load_lds16(gA1, lA1);
        load_lds16(gB0, lB0); load_lds16(gB1, lB1);
        gA0 += BK; gA1 += BK; gB0 += BK; gB1 += BK;
        __syncthreads();   // drains vmcnt before barrier

        f16x8 fa[4], fb[4];
        #pragma unroll
        for (int i = 0; i < 4; ++i) {
            int m = wm * 64 + i * 16 + l15;
            int cs = quad ^ ((m >> 1) & 3);
            fa[i] = *(const f16x8*)&lA[m * 32 + cs * 8];
        }
        #pragma unroll
        for (int j = 0; j < 4; ++j) {
            int n = wn * 64 + j * 16 + l15;
            int cs = quad ^ ((n >> 1) & 3);
            fb[j] = *(const f16x8*)&lB[n * 32 + cs * 8];
        }
        #pragma unroll
        for (int i = 0; i < 4; ++i)
            #pragma unroll
            for (int j = 0; j < 4; ++j)
                acc[i][j] = __builtin_amdgcn_mfma_f32_16x16x32_f16(fa[i], fb[j], acc[i][j], 0, 0, 0);
        __syncthreads();
    }

    if (EPI != 1) {
        #pragma unroll
        for (int i = 0; i < 4; ++i) {
            int row = bm * BM + wm * 64 + i * 16 + quad * 4;
            #pragma unroll
            for (int j = 0; j < 4; ++j) {
                int col = bn * BN + wn * 64 + j * 16 + l15;
                float bvv = bias[col];
                #pragma unroll
                for (int r = 0; r < 4; ++r) {
                    float val = acc[i][j][r] + bvv;
                    if (EPI == 0) ((u16*)Cp)[(long)(row + r) * N + col] = f2h(val);
                    else          ((float*)Cp)[(long)(row + r) * N + col] = val;
                }
            }
        }
    } else {
        #pragma unroll
        for (int i = 0; i < 4; ++i) {
            int dt = wm * 64 + i * 16 + quad * 4;
            #pragma unroll
            for (int j = 0; j < 4; ++j) {
                int ds = wn * 64 + j * 16 + l15;
                #pragma unroll
                for (int r = 0; r < 4; ++r)
                    atomicAdd(&diag[dt + r - ds + 127], acc[i][j][r]);
            }
        }
        __syncthreads();
        if (tid < 255) {
            int tau = ((bm - bn) * BM + tid - 127 + 2 * L_SEQ) & (L_SEQ - 1);
            atomicAdd(&corrOut[bz * L_SEQ + tau], diag[tid]);
        }
    }
}

// fp32 -> fp16, 8 elems/thread
__global__ __launch_bounds__(256) void convert_f16(const float* __restrict__ src, u16* __restrict__ dst)
{
    long i = (long)blockIdx.x * 256 + threadIdx.x;
    const float4* s4 = (const float4*)src;
    float4 a = s4[i * 2], b = s4[i * 2 + 1];
    union { uint4 u; _Float16 h[8]; } o;
    o.h[0] = (_Float16)a.x; o.h[1] = (_Float16)a.y;
    o.h[2] = (_Float16)a.z; o.h[3] = (_Float16)a.w;
    o.h[4] = (_Float16)b.x; o.h[5] = (_Float16)b.y;
    o.h[6] = (_Float16)b.z; o.h[7] = (_Float16)b.w;
    ((uint4*)dst)[i] = o.u;
}

// Wt[n][k] = W[k][n], fp32 -> fp16
__global__ __launch_bounds__(256) void transposeW(const float* __restrict__ src, u16* __restrict__ dst)
{
    __shared__ float t[32][33];
    int tx = threadIdx.x & 31, ty = threadIdx.x >> 5;
    int c0 = blockIdx.x * 32, r0 = blockIdx.y * 32;
    #pragma unroll
    for (int r = ty; r < 32; r += 8)
        t[r][tx] = src[(long)(r0 + r) * D_MODEL + c0 + tx];
    __syncthreads();
    #pragma unroll
    for (int r = ty; r < 32; r += 8)
        dst[(long)(c0 + r) * D_MODEL + r0 + tx] = f2h(t[tx][r]);
}

// One block. g[tau] = sum_b raw[b][tau]; top-7 (lowest-index tie-break);
// weights = raw[b][idx]/512 -> per-b softmax.
__global__ __launch_bounds__(256) void select_topk(
    const float* __restrict__ raw, int* __restrict__ selIdx, float* __restrict__ selW)
{
    __shared__ float g[L_SEQ];
    __shared__ float rv[256];
    __shared__ int   ri[256];
    __shared__ int   sidx[TOPK];
    __shared__ float wbuf[BATCH][TOPK];
    int tid = threadIdx.x;
    for (int t = tid; t < L_SEQ; t += 256) {
        float s = 0.0f;
        #pragma unroll
        for (int b = 0; b < BATCH; ++b) s += raw[b * L_SEQ + t];
        g[t] = s;
    }
    __syncthreads();
    for (int it = 0; it < TOPK; ++it) {
        float best = -1e30f; int bi = 0x7fffffff;
        for (int t = tid; t < L_SEQ; t += 256) {
            float v = g[t];
            if (v > best || (v == best && t < bi)) { best = v; bi = t; }
        }
        rv[tid] = best; ri[tid] = bi;
        __syncthreads();
        for (int s = 128; s > 0; s >>= 1) {
            if (tid < s) {
                float v2 = rv[tid + s]; int i2 = ri[tid + s];
                if (v2 > rv[tid] || (v2 == rv[tid] && i2 < ri[tid])) { rv[tid] = v2; ri[tid] = i2; }
            }
            __syncthreads();
        }
        if (tid == 0) { sidx[it] = ri[0]; g[ri[0]] = -1e30f; }
        __syncthreads();
    }
    if (tid < BATCH * TOPK) {
        int b = tid / TOPK, k = tid % TOPK;
        wbuf[b][k] = raw[b * L_SEQ + sidx[k]] * (1.0f / 512.0f);
    }
    __syncthreads();
    if (tid < BATCH) {
        float mx = -1e30f;
        #pragma unroll
        for (int k = 0; k < TOPK; ++k) mx = fmaxf(mx, wbuf[tid][k]);
        float e[TOPK]; float sum = 0.0f;
        #pragma unroll
        for (int k = 0; k < TOPK; ++k) { e[k] = expf(wbuf[tid][k] - mx); sum += e[k]; }
        #pragma unroll
        for (int k = 0; k < TOPK; ++k) selW[tid * TOPK + k] = e[k] / sum;
    }
    if (tid < TOPK) selIdx[tid] = sidx[tid];
}

// attn[b,l,:] = sum_k w[b][k] * V[b,(l+idx[k])%L,:]  (f16 in/out, 8 elems/thread)
__global__ __launch_bounds__(256) void gather_agg(
    const u16* __restrict__ V, const int* __restrict__ selIdx,
    const float* __restrict__ selW, u16* __restrict__ outB)
{
    __shared__ int si[TOPK];
    __shared__ float sw[TOPK];
    long flat = (long)blockIdx.x * 256 + threadIdx.x;     // over B*L*D/8 uint4s
    int b  = (int)(flat >> 17);                            // L*D/8 = 2^17 per b
    int l  = (int)((flat >> 6) & (L_SEQ - 1));
    int d8 = (int)(flat & 63);
    if (threadIdx.x < TOPK) {
        si[threadIdx.x] = selIdx[threadIdx.x];
        sw[threadIdx.x] = selW[b * TOPK + threadIdx.x];
    }
    __syncthreads();
    const uint4* v8 = (const uint4*)(V + (long)b * L_SEQ * D_MODEL);
    float a[8] = {0,0,0,0,0,0,0,0};
    #pragma unroll
    for (int k = 0; k < TOPK; ++k) {
        int src = (l + si[k]) & (L_SEQ - 1);
        union { uint4 u; _Float16 h[8]; } x;
        x.u = v8[src * 64 + d8];
        float w = sw[k];
        #pragma unroll
        for (int q = 0; q < 8; ++q) a[q] += w * (float)x.h[q];
    }
    union { uint4 u; _Float16 h[8]; } o;
    #pragma unroll
    for (int q = 0; q < 8; ++q) o.h[q] = (_Float16)a[q];
    ((uint4*)outB)[flat] = o.u;
}

extern "C" void kernel_launch(void* const* d_in, const int* in_sizes, int n_in,
                              void* d_out, int out_size, void* d_ws, size_t ws_size,
                              hipStream_t stream)
{
    (void)in_sizes; (void)n_in; (void)out_size; (void)ws_size;
    const float* Xq = (const float*)d_in[0];
    const float* Xk = (const float*)d_in[1];
    const float* Xv = (const float*)d_in[2];
    const float* Wq = (const float*)d_in[3];
    const float* bq = (const float*)d_in[4];
    const float* Wk = (const float*)d_in[5];
    const float* bk = (const float*)d_in[6];
    const float* Wv = (const float*)d_in[7];
    const float* bv = (const float*)d_in[8];
    const float* Wo = (const float*)d_in[9];
    const float* bo = (const float*)d_in[10];

    char* ws = (char*)d_ws;
    const long SLABH = (long)BATCH * L_SEQ * D_MODEL * sizeof(u16);   // 16 MB f16 slab
    u16* buf0 = (u16*)(ws);                    // Xq/Xk/Xv f16 (sequential), then attn
    u16* Qf   = (u16*)(ws + SLABH);
    u16* Kf   = (u16*)(ws + 2 * SLABH);
    u16* Vf   = (u16*)(ws + 3 * SLABH);
    const long WSZ = (long)D_MODEL * D_MODEL;
    u16* Wt   = (u16*)(ws + 4 * SLABH);        // 4 x 512 KB
    u16* Wqt = Wt + 0 * WSZ; u16* Wkt = Wt + 1 * WSZ;
    u16* Wvt = Wt + 2 * WSZ; u16* Wot = Wt + 3 * WSZ;
    float* raw = (float*)(ws + 4 * SLABH + 4 * WSZ * sizeof(u16));
    int*   sIdx = (int*)((char*)raw + (long)BATCH * L_SEQ * sizeof(float));
    float* sW   = (float*)(sIdx + 8);

    dim3 tb(256);
    transposeW<<<dim3(16, 16), tb, 0, stream>>>(Wq, Wqt);
    transposeW<<<dim3(16, 16), tb, 0, stream>>>(Wk, Wkt);
    transposeW<<<dim3(16, 16), tb, 0, stream>>>(Wv, Wvt);
    transposeW<<<dim3(16, 16), tb, 0, stream>>>(Wo, Wot);
    hipMemsetAsync(raw, 0, (long)BATCH * L_SEQ * sizeof(float), stream);

    dim3 gLin(D_MODEL / BN, (BATCH * L_SEQ) / BM, 1);   // (4, 128)
    const int nCvt = (int)(BATCH * L_SEQ * D_MODEL / 8 / 256);   // 4096

    convert_f16<<<nCvt, tb, 0, stream>>>(Xq, buf0);
    gemm_f16<0><<<gLin, tb, 0, stream>>>(buf0, Wqt, bq, Qf, nullptr, D_MODEL, D_MODEL, 0, 0);
    convert_f16<<<nCvt, tb, 0, stream>>>(Xk, buf0);
    gemm_f16<0><<<gLin, tb, 0, stream>>>(buf0, Wkt, bk, Kf, nullptr, D_MODEL, D_MODEL, 0, 0);
    convert_f16<<<nCvt, tb, 0, stream>>>(Xv, buf0);
    gemm_f16<0><<<gLin, tb, 0, stream>>>(buf0, Wvt, bv, Vf, nullptr, D_MODEL, D_MODEL, 0, 0);

    // Batched correlation Q K^T with wrapped-diagonal reduction -> raw[b][tau]
    dim3 gC(L_SEQ / BN, L_SEQ / BM, BATCH);             // (16, 16, 8)
    gemm_f16<1><<<gC, tb, 0, stream>>>(Qf, Kf, nullptr, nullptr, raw,
                                       L_SEQ, D_MODEL,
                                       (long)L_SEQ * D_MODEL, (long)L_SEQ * D_MODEL);

    select_topk<<<1, tb, 0, stream>>>(raw, sIdx, sW);

    gather_agg<<<nCvt, tb, 0, stream>>>(Vf, sIdx, sW, buf0);

    // Final projection: attn (f16) @ Wo^T + bo -> fp32 d_out
    gemm_f16<2><<<gLin, tb, 0, stream>>>(buf0, Wot, bo, d_out, nullptr, D_MODEL, D_MODEL, 0, 0);
}